// Round 2
// baseline (773.939 us; speedup 1.0000x reference)
//
#include <hip/hip_runtime.h>
#include <cmath>

#define NL 16
#define TABLE_SIZE (1u << 19)
#define TABLE_MASK (TABLE_SIZE - 1u)
#define P1 2654435761u
#define P2 805459861u

typedef float f2v __attribute__((ext_vector_type(2)));
typedef float f4v __attribute__((ext_vector_type(4)));

struct GridParams { float g[NL]; };

// ---------------- shared per-level math ----------------
__device__ __forceinline__ f2v level_eval(
    const float* __restrict__ tables, int l, float g,
    float px, float py, float pz, float qx, float qy, float qz)
{
  const float fx = floorf((qx + 1.f) / g);
  const float fy = floorf((qy + 1.f) / g);
  const float fz = floorf((qz + 1.f) / g);
  const float wx = (px - (fx * g - 1.f)) / g;
  const float wy = (py - (fy * g - 1.f)) / g;
  const float wz = (pz - (fz * g - 1.f)) / g;

  const unsigned hx0 = (unsigned)(int)fx;          // * PRIMES[0] == 1
  const unsigned hy0 = (unsigned)(int)fy * P1;
  const unsigned hz0 = (unsigned)(int)fz * P2;
  const unsigned hx1 = hx0 + 1u;
  const unsigned hy1 = hy0 + P1;
  const unsigned hz1 = hz0 + P2;

  const f2v* __restrict__ tab = (const f2v*)tables + (size_t)l * TABLE_SIZE;
  const f2v e000 = tab[(hx0 ^ hy0 ^ hz0) & TABLE_MASK];
  const f2v e001 = tab[(hx0 ^ hy0 ^ hz1) & TABLE_MASK];
  const f2v e010 = tab[(hx0 ^ hy1 ^ hz0) & TABLE_MASK];
  const f2v e011 = tab[(hx0 ^ hy1 ^ hz1) & TABLE_MASK];
  const f2v e100 = tab[(hx1 ^ hy0 ^ hz0) & TABLE_MASK];
  const f2v e101 = tab[(hx1 ^ hy0 ^ hz1) & TABLE_MASK];
  const f2v e110 = tab[(hx1 ^ hy1 ^ hz0) & TABLE_MASK];
  const f2v e111 = tab[(hx1 ^ hy1 ^ hz1) & TABLE_MASK];

  const float ux = 1.f - wx;
  const f2v a00 = e000 * ux + e100 * wx;
  const f2v a01 = e001 * ux + e101 * wx;
  const f2v a10 = e010 * ux + e110 * wx;
  const f2v a11 = e011 * ux + e111 * wx;
  const float uy = 1.f - wy;
  const f2v b0 = a00 * uy + a10 * wy;
  const f2v b1 = a01 * uy + a11 * wy;
  const float uz = 1.f - wz;
  return b0 * uz + b1 * wz;
}

// ---------------- level-major gather pass ----------------
// Computes levels [lo,hi) for all points; writes ws[l][n][2] (f2v), coalesced.
// Non-temporal on x and ws so L2 stays dedicated to the active table.
__global__ __launch_bounds__(256) void level_pass_kernel(
    const float* __restrict__ xin, const float* __restrict__ tables,
    f2v* __restrict__ ws, int npts, GridParams gp, int lo, int hi)
{
  int n = blockIdx.x * blockDim.x + threadIdx.x;
  if (n >= npts) return;

  const float px = __builtin_nontemporal_load(&xin[3 * n + 0]);
  const float py = __builtin_nontemporal_load(&xin[3 * n + 1]);
  const float pz = __builtin_nontemporal_load(&xin[3 * n + 2]);
  const float qx = fminf(fmaxf(px, -1.f), 1.f);
  const float qy = fminf(fmaxf(py, -1.f), 1.f);
  const float qz = fminf(fmaxf(pz, -1.f), 1.f);

  for (int l = lo; l < hi; ++l) {
    const f2v r = level_eval(tables, l, gp.g[l], px, py, pz, qx, qy, qz);
    __builtin_nontemporal_store(r, ws + (size_t)l * npts + n);
  }
}

// ---------------- transpose [16][N][2] -> [N][32] ----------------
__global__ __launch_bounds__(256) void transpose_kernel(
    const f2v* __restrict__ ws, float* __restrict__ out, int npts)
{
  int n = blockIdx.x * blockDim.x + threadIdx.x;
  if (n >= npts) return;
  f2v v[NL];
#pragma unroll
  for (int l = 0; l < NL; ++l)
    v[l] = __builtin_nontemporal_load(ws + (size_t)l * npts + n);
  f4v* o = (f4v*)(out + (size_t)n * 32);
#pragma unroll
  for (int i = 0; i < 8; ++i) {
    f4v t = { v[2 * i][0], v[2 * i][1], v[2 * i + 1][0], v[2 * i + 1][1] };
    __builtin_nontemporal_store(t, o + i);
  }
}

// ---------------- fallback: round-1 single-pass kernel ----------------
__global__ __launch_bounds__(256) void hash_embed_fused_kernel(
    const float* __restrict__ xin, const float* __restrict__ tables,
    float* __restrict__ out, int npts, GridParams gp)
{
  int n = blockIdx.x * blockDim.x + threadIdx.x;
  if (n >= npts) return;
  const float px = xin[3 * n + 0];
  const float py = xin[3 * n + 1];
  const float pz = xin[3 * n + 2];
  const float qx = fminf(fmaxf(px, -1.f), 1.f);
  const float qy = fminf(fmaxf(py, -1.f), 1.f);
  const float qz = fminf(fmaxf(pz, -1.f), 1.f);
  f2v acc[NL];
#pragma unroll
  for (int l = 0; l < NL; ++l)
    acc[l] = level_eval(tables, l, gp.g[l], px, py, pz, qx, qy, qz);
  f4v* o = (f4v*)(out + (size_t)n * 32);
#pragma unroll
  for (int i = 0; i < 8; ++i) {
    f4v t = { acc[2 * i][0], acc[2 * i][1], acc[2 * i + 1][0], acc[2 * i + 1][1] };
    o[i] = t;
  }
}

extern "C" void kernel_launch(void* const* d_in, const int* in_sizes, int n_in,
                              void* d_out, int out_size, void* d_ws, size_t ws_size,
                              hipStream_t stream) {
  const float* x = (const float*)d_in[0];
  const float* tables = (const float*)d_in[1];
  float* out = (float*)d_out;
  const int npts = in_sizes[0] / 3;

  GridParams gp;
  {
    const float b = expf((logf(512.0f) - logf(16.0f)) / 15.0f);
    for (int l = 0; l < NL; ++l) {
      const float r = floorf(16.0f * powf(b, (float)l));
      gp.g[l] = 2.0f / r;
    }
  }

  dim3 block(256);
  dim3 grid((npts + 255) / 256);

  const size_t ws_needed = (size_t)NL * npts * 2 * sizeof(float);
  if (ws_size >= ws_needed) {
    f2v* ws = (f2v*)d_ws;
    // Pass A: coarse levels 0..5 fused (aggregate working set ~2.2 MB, L2-resident)
    hipLaunchKernelGGL(level_pass_kernel, grid, block, 0, stream,
                       x, tables, ws, npts, gp, 0, 6);
    // One pass per fine level: the whole machine works on a single 4 MB table
    for (int l = 6; l < NL; ++l)
      hipLaunchKernelGGL(level_pass_kernel, grid, block, 0, stream,
                         x, tables, ws, npts, gp, l, l + 1);
    hipLaunchKernelGGL(transpose_kernel, grid, block, 0, stream, ws, out, npts);
  } else {
    hipLaunchKernelGGL(hash_embed_fused_kernel, grid, block, 0, stream,
                       x, tables, out, npts, gp);
  }
}

// Round 3
// 542.948 us; speedup vs baseline: 1.4254x; 1.4254x over previous
//
#include <hip/hip_runtime.h>
#include <cmath>

#define NL 16
#define NCOARSE 6
#define NFINE 10
#define TABLE_SIZE (1u << 19)
#define TABLE_MASK (TABLE_SIZE - 1u)
#define P1 2654435761u
#define P2 805459861u

typedef float f2v __attribute__((ext_vector_type(2)));
typedef float f4v __attribute__((ext_vector_type(4)));
typedef unsigned long long u64;

struct GridParams { float g[NL]; };

// L2-direct (L1-bypassing) 8B gather: random gathers never hit L1, and full
// 64B L1 line fills would burn L2->L1 bandwidth 8x over the useful bytes.
__device__ __forceinline__ f2v ld_agent(const f2v* p) {
  u64 raw = __hip_atomic_load((const u64*)p, __ATOMIC_RELAXED, __HIP_MEMORY_SCOPE_AGENT);
  union { u64 u; f2v f; } c; c.u = raw; return c.f;
}

struct Corners { unsigned idx[8]; float wx, wy, wz; };

__device__ __forceinline__ Corners make_corners(
    float g, float px, float py, float pz, float qx, float qy, float qz)
{
  Corners c;
  const float fx = floorf((qx + 1.f) / g);
  const float fy = floorf((qy + 1.f) / g);
  const float fz = floorf((qz + 1.f) / g);
  c.wx = (px - (fx * g - 1.f)) / g;
  c.wy = (py - (fy * g - 1.f)) / g;
  c.wz = (pz - (fz * g - 1.f)) / g;
  const unsigned hx0 = (unsigned)(int)fx;         // * PRIMES[0] == 1
  const unsigned hy0 = (unsigned)(int)fy * P1;
  const unsigned hz0 = (unsigned)(int)fz * P2;
  const unsigned hx1 = hx0 + 1u;
  const unsigned hy1 = hy0 + P1;
  const unsigned hz1 = hz0 + P2;
  c.idx[0] = (hx0 ^ hy0 ^ hz0) & TABLE_MASK;
  c.idx[1] = (hx0 ^ hy0 ^ hz1) & TABLE_MASK;
  c.idx[2] = (hx0 ^ hy1 ^ hz0) & TABLE_MASK;
  c.idx[3] = (hx0 ^ hy1 ^ hz1) & TABLE_MASK;
  c.idx[4] = (hx1 ^ hy0 ^ hz0) & TABLE_MASK;
  c.idx[5] = (hx1 ^ hy0 ^ hz1) & TABLE_MASK;
  c.idx[6] = (hx1 ^ hy1 ^ hz0) & TABLE_MASK;
  c.idx[7] = (hx1 ^ hy1 ^ hz1) & TABLE_MASK;
  return c;
}

__device__ __forceinline__ f2v trilerp(const f2v e[8], float wx, float wy, float wz) {
  const float ux = 1.f - wx;
  const f2v a00 = e[0] * ux + e[4] * wx;
  const f2v a01 = e[1] * ux + e[5] * wx;
  const f2v a10 = e[2] * ux + e[6] * wx;
  const f2v a11 = e[3] * ux + e[7] * wx;
  const float uy = 1.f - wy;
  const f2v b0 = a00 * uy + a10 * wy;
  const f2v b1 = a01 * uy + a11 * wy;
  const float uz = 1.f - wz;
  return b0 * uz + b1 * wz;
}

// ---------- fine level pass: one level, 2 points/thread, L1-bypass gathers ----------
__global__ __launch_bounds__(256) void fine_pass_kernel(
    const float* __restrict__ xin, const f2v* __restrict__ tab,
    f2v* __restrict__ wsl, int npts, int strideT, float g)
{
  const int n0 = blockIdx.x * 256 + threadIdx.x;
  const int n1 = n0 + strideT;
  const int c0 = n0 < npts ? n0 : npts - 1;
  const int c1 = n1 < npts ? n1 : npts - 1;

  const float px0 = xin[3 * c0 + 0], py0 = xin[3 * c0 + 1], pz0 = xin[3 * c0 + 2];
  const float px1 = xin[3 * c1 + 0], py1 = xin[3 * c1 + 1], pz1 = xin[3 * c1 + 2];
  const float qx0 = fminf(fmaxf(px0, -1.f), 1.f), qy0 = fminf(fmaxf(py0, -1.f), 1.f), qz0 = fminf(fmaxf(pz0, -1.f), 1.f);
  const float qx1 = fminf(fmaxf(px1, -1.f), 1.f), qy1 = fminf(fmaxf(py1, -1.f), 1.f), qz1 = fminf(fmaxf(pz1, -1.f), 1.f);

  const Corners ca = make_corners(g, px0, py0, pz0, qx0, qy0, qz0);
  const Corners cb = make_corners(g, px1, py1, pz1, qx1, qy1, qz1);

  // issue all 16 gathers before consuming any (MLP)
  f2v ea[8], eb[8];
#pragma unroll
  for (int j = 0; j < 8; ++j) ea[j] = ld_agent(tab + ca.idx[j]);
#pragma unroll
  for (int j = 0; j < 8; ++j) eb[j] = ld_agent(tab + cb.idx[j]);

  const f2v ra = trilerp(ea, ca.wx, ca.wy, ca.wz);
  const f2v rb = trilerp(eb, cb.wx, cb.wy, cb.wz);

  if (n0 < npts) __builtin_nontemporal_store(ra, wsl + n0);
  if (n1 < npts) __builtin_nontemporal_store(rb, wsl + n1);
}

// ---------- finalize: coarse levels inline + ws read + LDS transpose + coalesced out ----------
__global__ __launch_bounds__(256) void finalize_kernel(
    const float* __restrict__ xin, const float* __restrict__ tables,
    const f2v* __restrict__ ws, float* __restrict__ out, int npts, GridParams gp)
{
  __shared__ f2v lds[NL][257];   // pad: conflict-free b64 in both phases
  const int t = threadIdx.x;
  const int base = blockIdx.x * 256;
  const int n = base + t;

  if (n < npts) {
    const float px = xin[3 * n + 0], py = xin[3 * n + 1], pz = xin[3 * n + 2];
    const float qx = fminf(fmaxf(px, -1.f), 1.f);
    const float qy = fminf(fmaxf(py, -1.f), 1.f);
    const float qz = fminf(fmaxf(pz, -1.f), 1.f);
#pragma unroll
    for (int l = 0; l < NCOARSE; ++l) {
      const Corners c = make_corners(gp.g[l], px, py, pz, qx, qy, qz);
      const f2v* tab = (const f2v*)tables + (size_t)l * TABLE_SIZE;
      f2v e[8];
#pragma unroll
      for (int j = 0; j < 8; ++j) e[j] = tab[c.idx[j]];   // plain loads: L1/L2 resident
      lds[l][t] = trilerp(e, c.wx, c.wy, c.wz);
    }
#pragma unroll
    for (int li = 0; li < NFINE; ++li)
      lds[NCOARSE + li][t] = __builtin_nontemporal_load(ws + (size_t)li * npts + n);
  }
  __syncthreads();

  // block's out region = 256 pts * 128 B = 32 KB contiguous; write as f4 chunks,
  // lane-consecutive chunks -> 1 KB contiguous per wave-instruction.
#pragma unroll
  for (int k = 0; k < 8; ++k) {
    const int j4 = t + 256 * k;      // f4-chunk id within block, 0..2047
    const int p  = j4 >> 3;          // point within block
    const int lp = j4 & 7;           // which f2v pair
    if (base + p < npts) {
      const f2v a = lds[2 * lp + 0][p];
      const f2v b = lds[2 * lp + 1][p];
      const f4v v = { a[0], a[1], b[0], b[1] };
      __builtin_nontemporal_store(v, (f4v*)(out + (size_t)base * 32) + j4);
    }
  }
}

// ---------- fallback: round-1 fused kernel (if ws too small) ----------
__global__ __launch_bounds__(256) void hash_embed_fused_kernel(
    const float* __restrict__ xin, const float* __restrict__ tables,
    float* __restrict__ out, int npts, GridParams gp)
{
  int n = blockIdx.x * blockDim.x + threadIdx.x;
  if (n >= npts) return;
  const float px = xin[3 * n + 0], py = xin[3 * n + 1], pz = xin[3 * n + 2];
  const float qx = fminf(fmaxf(px, -1.f), 1.f);
  const float qy = fminf(fmaxf(py, -1.f), 1.f);
  const float qz = fminf(fmaxf(pz, -1.f), 1.f);
  f2v acc[NL];
#pragma unroll
  for (int l = 0; l < NL; ++l) {
    const Corners c = make_corners(gp.g[l], px, py, pz, qx, qy, qz);
    const f2v* tab = (const f2v*)tables + (size_t)l * TABLE_SIZE;
    f2v e[8];
#pragma unroll
    for (int j = 0; j < 8; ++j) e[j] = tab[c.idx[j]];
    acc[l] = trilerp(e, c.wx, c.wy, c.wz);
  }
  f4v* o = (f4v*)(out + (size_t)n * 32);
#pragma unroll
  for (int i = 0; i < 8; ++i) {
    f4v v = { acc[2 * i][0], acc[2 * i][1], acc[2 * i + 1][0], acc[2 * i + 1][1] };
    o[i] = v;
  }
}

extern "C" void kernel_launch(void* const* d_in, const int* in_sizes, int n_in,
                              void* d_out, int out_size, void* d_ws, size_t ws_size,
                              hipStream_t stream) {
  const float* x = (const float*)d_in[0];
  const float* tables = (const float*)d_in[1];
  float* out = (float*)d_out;
  const int npts = in_sizes[0] / 3;

  GridParams gp;
  {
    const float b = expf((logf(512.0f) - logf(16.0f)) / 15.0f);
    for (int l = 0; l < NL; ++l) {
      const float r = floorf(16.0f * powf(b, (float)l));
      gp.g[l] = 2.0f / r;
    }
  }

  const size_t ws_needed = (size_t)NFINE * npts * sizeof(f2v);
  if (ws_size >= ws_needed) {
    f2v* ws = (f2v*)d_ws;
    const int gridF = (npts + 511) / 512;      // 2 points per thread
    const int strideT = gridF * 256;
    for (int l = NCOARSE; l < NL; ++l) {
      const f2v* tab = (const f2v*)tables + (size_t)l * TABLE_SIZE;
      f2v* wsl = ws + (size_t)(l - NCOARSE) * npts;
      hipLaunchKernelGGL(fine_pass_kernel, dim3(gridF), dim3(256), 0, stream,
                         x, tab, wsl, npts, strideT, gp.g[l]);
    }
    const int gridZ = (npts + 255) / 256;
    hipLaunchKernelGGL(finalize_kernel, dim3(gridZ), dim3(256), 0, stream,
                       x, tables, ws, out, npts, gp);
  } else {
    const int grid = (npts + 255) / 256;
    hipLaunchKernelGGL(hash_embed_fused_kernel, dim3(grid), dim3(256), 0, stream,
                       x, tables, out, npts, gp);
  }
}

// Round 4
// 520.373 us; speedup vs baseline: 1.4873x; 1.0434x over previous
//
#include <hip/hip_runtime.h>
#include <cmath>

#define NL 16
#define NPAIR 7          // levels 0..6: dense voxel-indexed z-pair tables
#define TABLE_SIZE (1u << 19)
#define TABLE_MASK (TABLE_SIZE - 1u)
#define P1 2654435761u
#define P2 805459861u

typedef float f2v __attribute__((ext_vector_type(2)));
typedef float f4v __attribute__((ext_vector_type(4)));
typedef unsigned long long u64;

struct Params {
  float g[NL];
  int R[NPAIR];
  unsigned off[NPAIR];   // pair-table offsets, in 16B units
  unsigned nE[NPAIR];
  unsigned totE;
};

// L2-direct 8B gather (bypass L1: random gathers never hit L1; line fills waste BW)
__device__ __forceinline__ f2v ld_agent(const f2v* p) {
  u64 raw = __hip_atomic_load((const u64*)p, __ATOMIC_RELAXED, __HIP_MEMORY_SCOPE_AGENT);
  union { u64 u; f2v f; } c; c.u = raw; return c.f;
}

struct Corners { unsigned idx[8]; float wx, wy, wz; };

__device__ __forceinline__ Corners make_corners(
    float g, float px, float py, float pz, float qx, float qy, float qz)
{
  Corners c;
  const float fx = floorf((qx + 1.f) / g);
  const float fy = floorf((qy + 1.f) / g);
  const float fz = floorf((qz + 1.f) / g);
  c.wx = (px - (fx * g - 1.f)) / g;
  c.wy = (py - (fy * g - 1.f)) / g;
  c.wz = (pz - (fz * g - 1.f)) / g;
  const unsigned hx0 = (unsigned)(int)fx;          // * PRIMES[0] == 1
  const unsigned hy0 = (unsigned)(int)fy * P1;
  const unsigned hz0 = (unsigned)(int)fz * P2;
  const unsigned hx1 = hx0 + 1u;
  const unsigned hy1 = hy0 + P1;
  const unsigned hz1 = hz0 + P2;
  c.idx[0] = (hx0 ^ hy0 ^ hz0) & TABLE_MASK;
  c.idx[1] = (hx0 ^ hy0 ^ hz1) & TABLE_MASK;
  c.idx[2] = (hx0 ^ hy1 ^ hz0) & TABLE_MASK;
  c.idx[3] = (hx0 ^ hy1 ^ hz1) & TABLE_MASK;
  c.idx[4] = (hx1 ^ hy0 ^ hz0) & TABLE_MASK;
  c.idx[5] = (hx1 ^ hy0 ^ hz1) & TABLE_MASK;
  c.idx[6] = (hx1 ^ hy1 ^ hz0) & TABLE_MASK;
  c.idx[7] = (hx1 ^ hy1 ^ hz1) & TABLE_MASK;
  return c;
}

__device__ __forceinline__ f2v trilerp(const f2v e[8], float wx, float wy, float wz) {
  const float ux = 1.f - wx;
  const f2v a00 = e[0] * ux + e[4] * wx;
  const f2v a01 = e[1] * ux + e[5] * wx;
  const f2v a10 = e[2] * ux + e[6] * wx;
  const f2v a11 = e[3] * ux + e[7] * wx;
  const float uy = 1.f - wy;
  const f2v b0 = a00 * uy + a10 * wy;
  const f2v b1 = a01 * uy + a11 * wy;
  const float uz = 1.f - wz;
  return b0 * uz + b1 * wz;
}

// dense pair-table eval: 4 aligned 16B loads (each = 2 z-corners)
__device__ __forceinline__ f2v pair_eval(
    const f4v* __restrict__ pt, int R, float g,
    float px, float py, float pz, float qx, float qy, float qz)
{
  const float fx = floorf((qx + 1.f) / g);
  const float fy = floorf((qy + 1.f) / g);
  const float fz = floorf((qz + 1.f) / g);
  const float wx = (px - (fx * g - 1.f)) / g;
  const float wy = (py - (fy * g - 1.f)) / g;
  const float wz = (pz - (fz * g - 1.f)) / g;
  const int bx = (int)fx, by = (int)fy, bz = (int)fz;
  const int s = R + 1;                       // z-pair dim
  const int base = (bx * (R + 2) + by) * s + bz;
  const f4v p00 = pt[base];                  // (x0,y0)
  const f4v p01 = pt[base + s];              // (x0,y1)
  const f4v p10 = pt[base + (R + 2) * s];    // (x1,y0)
  const f4v p11 = pt[base + (R + 3) * s];    // (x1,y1)
  const float uz = 1.f - wz;
  const f2v a00 = { p00[0] * uz + p00[2] * wz, p00[1] * uz + p00[3] * wz };
  const f2v a01 = { p01[0] * uz + p01[2] * wz, p01[1] * uz + p01[3] * wz };
  const f2v a10 = { p10[0] * uz + p10[2] * wz, p10[1] * uz + p10[3] * wz };
  const f2v a11 = { p11[0] * uz + p11[2] * wz, p11[1] * uz + p11[3] * wz };
  const float uy = 1.f - wy;
  const f2v b0 = a00 * uy + a01 * wy;
  const f2v b1 = a10 * uy + a11 * wy;
  const float ux = 1.f - wx;
  return b0 * ux + b1 * wx;
}

// ---------- build dense z-pair tables for levels 0..6 ----------
__global__ __launch_bounds__(256) void rehash_kernel(
    const float* __restrict__ tables, f4v* __restrict__ pt, Params P)
{
  unsigned tid = blockIdx.x * 256 + threadIdx.x;
  if (tid >= P.totE) return;
  int l = 0; unsigned e = tid;
  while (e >= P.nE[l]) { e -= P.nE[l]; ++l; }
  const unsigned R = (unsigned)P.R[l];
  const unsigned vz = e % (R + 1u);
  const unsigned t2 = e / (R + 1u);
  const unsigned vy = t2 % (R + 2u);
  const unsigned vx = t2 / (R + 2u);
  const f2v* tab = (const f2v*)tables + (size_t)l * TABLE_SIZE;
  const unsigned h0 = (vx ^ (vy * P1) ^ (vz * P2)) & TABLE_MASK;
  const unsigned h1 = (vx ^ (vy * P1) ^ ((vz + 1u) * P2)) & TABLE_MASK;
  const f2v a = tab[h0], b = tab[h1];
  const f4v o = { a[0], a[1], b[0], b[1] };
  pt[P.off[l] + e] = o;
}

// ---------- coarse fused pass: levels 0..4 via pair tables ----------
__global__ __launch_bounds__(256) void coarse_pass_kernel(
    const float* __restrict__ xin, const f4v* __restrict__ pt,
    f2v* __restrict__ ws, int npts, Params P)
{
  const int n = blockIdx.x * 256 + threadIdx.x;
  if (n >= npts) return;
  const float px = __builtin_nontemporal_load(&xin[3 * n + 0]);
  const float py = __builtin_nontemporal_load(&xin[3 * n + 1]);
  const float pz = __builtin_nontemporal_load(&xin[3 * n + 2]);
  const float qx = fminf(fmaxf(px, -1.f), 1.f);
  const float qy = fminf(fmaxf(py, -1.f), 1.f);
  const float qz = fminf(fmaxf(pz, -1.f), 1.f);
#pragma unroll
  for (int l = 0; l < 5; ++l) {
    const f2v r = pair_eval(pt + P.off[l], P.R[l], P.g[l], px, py, pz, qx, qy, qz);
    __builtin_nontemporal_store(r, ws + (size_t)l * npts + n);
  }
}

// ---------- single-level pair pass (l5, l6), 2 pts/thread ----------
__global__ __launch_bounds__(256) void pair_pass_kernel(
    const float* __restrict__ xin, const f4v* __restrict__ pt,
    f2v* __restrict__ wsl, int npts, int strideT, int R, float g)
{
  const int n0 = blockIdx.x * 256 + threadIdx.x;
  const int n1 = n0 + strideT;
  const int c0 = n0 < npts ? n0 : npts - 1;
  const int c1 = n1 < npts ? n1 : npts - 1;
  const float px0 = xin[3 * c0 + 0], py0 = xin[3 * c0 + 1], pz0 = xin[3 * c0 + 2];
  const float px1 = xin[3 * c1 + 0], py1 = xin[3 * c1 + 1], pz1 = xin[3 * c1 + 2];
  const float qx0 = fminf(fmaxf(px0, -1.f), 1.f), qy0 = fminf(fmaxf(py0, -1.f), 1.f), qz0 = fminf(fmaxf(pz0, -1.f), 1.f);
  const float qx1 = fminf(fmaxf(px1, -1.f), 1.f), qy1 = fminf(fmaxf(py1, -1.f), 1.f), qz1 = fminf(fmaxf(pz1, -1.f), 1.f);
  const f2v r0 = pair_eval(pt, R, g, px0, py0, pz0, qx0, qy0, qz0);
  const f2v r1 = pair_eval(pt, R, g, px1, py1, pz1, qx1, qy1, qz1);
  if (n0 < npts) __builtin_nontemporal_store(r0, wsl + n0);
  if (n1 < npts) __builtin_nontemporal_store(r1, wsl + n1);
}

// ---------- fine hashed pass: one level, 4 pts/thread ----------
__global__ __launch_bounds__(256) void fine_pass_kernel(
    const float* __restrict__ xin, const f2v* __restrict__ tab,
    f2v* __restrict__ wsl, int npts, int strideT, float g)
{
  const int nb = blockIdx.x * 256 + threadIdx.x;
  int n[4], c[4];
#pragma unroll
  for (int i = 0; i < 4; ++i) {
    n[i] = nb + i * strideT;
    c[i] = n[i] < npts ? n[i] : npts - 1;
  }
  Corners cr[4];
#pragma unroll
  for (int i = 0; i < 4; ++i) {
    const float px = xin[3 * c[i] + 0], py = xin[3 * c[i] + 1], pz = xin[3 * c[i] + 2];
    const float qx = fminf(fmaxf(px, -1.f), 1.f);
    const float qy = fminf(fmaxf(py, -1.f), 1.f);
    const float qz = fminf(fmaxf(pz, -1.f), 1.f);
    cr[i] = make_corners(g, px, py, pz, qx, qy, qz);
  }
  f2v e[4][8];
#pragma unroll
  for (int i = 0; i < 4; ++i)
#pragma unroll
    for (int j = 0; j < 8; ++j) e[i][j] = ld_agent(tab + cr[i].idx[j]);
#pragma unroll
  for (int i = 0; i < 4; ++i) {
    const f2v r = trilerp(e[i], cr[i].wx, cr[i].wy, cr[i].wz);
    if (n[i] < npts) __builtin_nontemporal_store(r, wsl + n[i]);
  }
}

// ---------- pure transpose: ws [16][N][2] -> out [N][32] ----------
__global__ __launch_bounds__(256) void transpose_kernel(
    const f2v* __restrict__ ws, float* __restrict__ out, int npts)
{
  __shared__ f2v lds[NL][257];
  const int t = threadIdx.x;
  const int base = blockIdx.x * 256;
  const int n = base + t;
  if (n < npts) {
#pragma unroll
    for (int l = 0; l < NL; ++l)
      lds[l][t] = __builtin_nontemporal_load(ws + (size_t)l * npts + n);
  }
  __syncthreads();
#pragma unroll
  for (int k = 0; k < 8; ++k) {
    const int j4 = t + 256 * k;
    const int p = j4 >> 3;
    const int lp = j4 & 7;
    if (base + p < npts) {
      const f2v a = lds[2 * lp + 0][p];
      const f2v b = lds[2 * lp + 1][p];
      const f4v v = { a[0], a[1], b[0], b[1] };
      __builtin_nontemporal_store(v, (f4v*)(out + (size_t)base * 32) + j4);
    }
  }
}

// ---------- fallback: fused single-pass ----------
__global__ __launch_bounds__(256) void hash_embed_fused_kernel(
    const float* __restrict__ xin, const float* __restrict__ tables,
    float* __restrict__ out, int npts, Params P)
{
  int n = blockIdx.x * blockDim.x + threadIdx.x;
  if (n >= npts) return;
  const float px = xin[3 * n + 0], py = xin[3 * n + 1], pz = xin[3 * n + 2];
  const float qx = fminf(fmaxf(px, -1.f), 1.f);
  const float qy = fminf(fmaxf(py, -1.f), 1.f);
  const float qz = fminf(fmaxf(pz, -1.f), 1.f);
  f2v acc[NL];
#pragma unroll
  for (int l = 0; l < NL; ++l) {
    const Corners c = make_corners(P.g[l], px, py, pz, qx, qy, qz);
    const f2v* tab = (const f2v*)tables + (size_t)l * TABLE_SIZE;
    f2v e[8];
#pragma unroll
    for (int j = 0; j < 8; ++j) e[j] = tab[c.idx[j]];
    acc[l] = trilerp(e, c.wx, c.wy, c.wz);
  }
  f4v* o = (f4v*)(out + (size_t)n * 32);
#pragma unroll
  for (int i = 0; i < 8; ++i) {
    const f4v v = { acc[2 * i][0], acc[2 * i][1], acc[2 * i + 1][0], acc[2 * i + 1][1] };
    o[i] = v;
  }
}

extern "C" void kernel_launch(void* const* d_in, const int* in_sizes, int n_in,
                              void* d_out, int out_size, void* d_ws, size_t ws_size,
                              hipStream_t stream) {
  const float* x = (const float*)d_in[0];
  const float* tables = (const float*)d_in[1];
  float* out = (float*)d_out;
  const int npts = in_sizes[0] / 3;

  Params P;
  {
    const float b = expf((logf(512.0f) - logf(16.0f)) / 15.0f);
    unsigned off = 0;
    for (int l = 0; l < NL; ++l) {
      const float r = floorf(16.0f * powf(b, (float)l));
      P.g[l] = 2.0f / r;
      if (l < NPAIR) {
        const int R = (int)r;
        P.R[l] = R;
        P.nE[l] = (unsigned)((R + 2) * (R + 2) * (R + 1));
        P.off[l] = off;
        off += P.nE[l];
      }
    }
    P.totE = off;   // ~566K entries = ~9.06 MB of f4v
  }

  const size_t ws_needed = (size_t)NL * npts * sizeof(f2v);
  const size_t pair_bytes = (size_t)P.totE * sizeof(f4v);
  const size_t out_bytes = (size_t)out_size * sizeof(float);

  if (ws_size >= ws_needed && out_bytes >= pair_bytes) {
    f2v* ws = (f2v*)d_ws;
    f4v* pt = (f4v*)d_out;   // pair tables live in d_out head; the transpose
                             // (last kernel) overwrites all of d_out — stream-ordered safe.

    hipLaunchKernelGGL(rehash_kernel, dim3((P.totE + 255) / 256), dim3(256), 0, stream,
                       tables, pt, P);

    hipLaunchKernelGGL(coarse_pass_kernel, dim3((npts + 255) / 256), dim3(256), 0, stream,
                       x, pt, ws, npts, P);

    const int grid2 = (npts + 511) / 512;
    const int stride2 = grid2 * 256;
    for (int l = 5; l < NPAIR; ++l)
      hipLaunchKernelGGL(pair_pass_kernel, dim3(grid2), dim3(256), 0, stream,
                         x, pt + P.off[l], ws + (size_t)l * npts, npts, stride2,
                         P.R[l], P.g[l]);

    const int grid4 = (npts + 1023) / 1024;
    const int stride4 = grid4 * 256;
    for (int l = NPAIR; l < NL; ++l)
      hipLaunchKernelGGL(fine_pass_kernel, dim3(grid4), dim3(256), 0, stream,
                         x, (const f2v*)tables + (size_t)l * TABLE_SIZE,
                         ws + (size_t)l * npts, npts, stride4, P.g[l]);

    hipLaunchKernelGGL(transpose_kernel, dim3((npts + 255) / 256), dim3(256), 0, stream,
                       ws, out, npts);
  } else {
    hipLaunchKernelGGL(hash_embed_fused_kernel, dim3((npts + 255) / 256), dim3(256), 0, stream,
                       x, tables, out, npts, P);
  }
}